// Round 5
// baseline (176.716 us; speedup 1.0000x reference)
//
#include <hip/hip_runtime.h>
#include <cstddef>

#define NB 512
#define NS 2048
#define NK 17
#define CL 8             // owned steps per chunk (one chunk per LANE) -> 1.5 MV/step
#define NW 4             // warmup steps (contraction^4 ~6e-6 << fp16 chain floor)
#define HT 1024          // copy rows per block (half sequence)
#define SP 8             // staged pre-roll rows before first owned chunk
#define NLT (HT + SP)    // max staged rows = 1032
#define CHUNKD 37        // dwords per 4-row group: 4 x 9 + 1 pad (37%32=5)
#define ROWD 9           // dwords per row (18 halves: 17 + 1 pad)
#define LDS_DW ((NLT / 4) * CHUNKD)   // 258*37 = 9546 dwords = 38184 B

typedef __fp16 h2 __attribute__((ext_vector_type(2)));
typedef float  f4 __attribute__((ext_vector_type(4)));
union UH { unsigned int u; h2 h; };

// Block 0: Mg[kk*17+n] = half2( exp(T[2kk][n]), exp(T[2kk+1][n]) ), kk=8 hi = 0.
// Blocks 1..NB: lens[b] = sum(attn[b,:])  (mask is a prefix).
__global__ void prep_k(const float* __restrict__ trans, const int* __restrict__ attn,
                       unsigned int* __restrict__ Mg, int* __restrict__ lens) {
    __shared__ int red[4];
    const int tid = threadIdx.x;
    if (blockIdx.x == 0) {
        if (tid < 9 * NK) {
            int kk = tid / NK, n = tid % NK;
            float lo = __expf(trans[(2 * kk) * NK + n]);
            float hi = (kk < 8) ? __expf(trans[(2 * kk + 1) * NK + n]) : 0.f;
            UH u; u.h = __builtin_amdgcn_cvt_pkrtz(lo, hi);
            Mg[tid] = u.u;
        }
        return;
    }
    const int b = blockIdx.x - 1;
    const int4* __restrict__ a4 = (const int4*)(attn + (size_t)b * NS);
    int4 x = a4[tid];
    int4 y = a4[tid + 256];
    int s = x.x + x.y + x.z + x.w + y.x + y.y + y.z + y.w;
#pragma unroll
    for (int off = 32; off >= 1; off >>= 1) s += __shfl_down(s, off, 64);
    if ((tid & 63) == 0) red[tid >> 6] = s;
    __syncthreads();
    if (tid == 0) lens[b] = red[0] + red[1] + red[2] + red[3];
}

// Balanced pair split: CT=ceil(len/8) chunks; block h of pair owns chunks
// [h?C0:0, h?CT:C0), C0=(CT+1)/2.  Each block: fixed 1024-row copy slab +
// ~len/2 staged rows + ~CT/2 chain lanes + matching numerator range.
__global__ __launch_bounds__(256, 4) void crf_fused(
    const float* __restrict__ emis,
    const float* __restrict__ startT,
    const float* __restrict__ endT,
    const float* __restrict__ trans,
    const int*   __restrict__ labels,
    const int*   __restrict__ lens,
    const unsigned int* __restrict__ Mg,
    float*       __restrict__ outE,      // d_out + 1
    float*       __restrict__ out)       // d_out[0], pre-zeroed
{
    __shared__ unsigned int expE[LDS_DW];
    float* red = (float*)expE;           // aliased: expE dead before reduction

    const int tid = threadIdx.x;
    const int b  = blockIdx.x >> 1;
    const int h  = blockIdx.x & 1;
    const int len = lens[b];

    const int CT = (len + 7) >> 3;       // total chunks (>=1)
    const int C0 = (CT + 1) >> 1;        // chunks owned by block 0
    const int chunkBase = h ? C0 : 0;
    const int chunkEnd  = h ? CT : C0;
    const int ltBase = chunkBase * 8 - SP;   // staged row lt = t - ltBase

    const size_t ebOff = (size_t)b * NS * NK;
    const float* __restrict__ eb = emis + ebOff;
    float*       __restrict__ ob = outE + ebOff;
    const int*   __restrict__ lb = labels + (size_t)b * NS;

    // ---- phase 0: fixed copy slab [h*1024, h*1024+1024) rows, depth-4 rotation ----
    {
        const int ownF = (h << 10) * NK;         // h*1024*17, multiple of 4
        const float* __restrict__ src = eb + ownF;
        float*       __restrict__ dst = ob + ownF;
        const int base = tid * 4;                // 17408 floats = 17 f4 per thread
        f4 r0 = *(const f4*)(src + base);
        f4 r1 = *(const f4*)(src + base + 1024);
        f4 r2 = *(const f4*)(src + base + 2048);
        f4 r3 = *(const f4*)(src + base + 3072);
#pragma unroll
        for (int k = 0; k < 3; ++k) {
            const int o = k * 4096 + base;
            f4 n0 = *(const f4*)(src + o + 4096);
            f4 n1 = *(const f4*)(src + o + 5120);
            f4 n2 = *(const f4*)(src + o + 6144);
            f4 n3 = *(const f4*)(src + o + 7168);
            __builtin_nontemporal_store(r0, (f4*)(dst + o));
            __builtin_nontemporal_store(r1, (f4*)(dst + o + 1024));
            __builtin_nontemporal_store(r2, (f4*)(dst + o + 2048));
            __builtin_nontemporal_store(r3, (f4*)(dst + o + 3072));
            r0 = n0; r1 = n1; r2 = n2; r3 = n3;
        }
        const int o = 12288 + base;
        f4 n0 = *(const f4*)(src + o + 4096);    // k=16 tail
        __builtin_nontemporal_store(r0, (f4*)(dst + o));
        __builtin_nontemporal_store(r1, (f4*)(dst + o + 1024));
        __builtin_nontemporal_store(r2, (f4*)(dst + o + 2048));
        __builtin_nontemporal_store(r3, (f4*)(dst + o + 3072));
        __builtin_nontemporal_store(n0, (f4*)(dst + o + 4096));
    }

    // ---- phase 1: staging of owned live rows [TL0, Tstop) -> LDS half(exp(e)) ----
    {
        const int TL0   = h ? (C0 * 8 - SP) : 0;             // multiple of 8
        const int Tstop = h ? len : (C0 * 8 < len ? C0 * 8 : len);
        const int startF = TL0 * NK;                          // multiple of 4
        const int stopF  = Tstop * NK;
        int g = startF + tid * 4;
        int t4  = (int)((unsigned)g / 17u);
        int n4  = g - t4 * 17;
        int lt4 = t4 - ltBase;
        f4 v = {0.f, 0.f, 0.f, 0.f};
        if (g < stopF) v = *(const f4*)(eb + g);
        while (g < stopF) {
            const int gn = g + 1024;
            f4 vn = v;
            if (gn < stopF) vn = *(const f4*)(eb + gn);   // prefetch stays in flight
            float ev[4] = {v.x, v.y, v.z, v.w};
            int lt = lt4, nn = n4;
#pragma unroll
            for (int u = 0; u < 4; ++u) {
                if (g + u < stopF) {
                    int ha = ((lt >> 2) * CHUNKD + (lt & 3) * ROWD) * 2 + nn;
                    ((__fp16*)expE)[ha] = (__fp16)__expf(ev[u]);
                }
                ++nn; if (nn == 17) { nn = 0; ++lt; }
            }
            lt4 += 60; n4 += 4; if (n4 >= 17) { n4 -= 17; ++lt4; }   // +1024 floats
            v = vn; g = gn;
        }
    }
    __syncthreads();

    // ---- phase 2 (role-split): chains on waves 0-1, numerator on waves 2-3 ----
    float numA = 0.f, zc = 0.f;

    if (tid >= 128) {
        // numerator over this block's owned timestep range
        const int tg0 = chunkBase * 8;
        const int tg1 = h ? len : (C0 * 8 < len ? C0 * 8 : len);
        int t = tg0 + (tid - 128);
#pragma unroll
        for (int j = 0; j < 8; ++j, t += 128) {
            if (t < tg1) {
                int la = lb[t];
                numA += eb[(size_t)t * NK + la];
                numA += (t == 0) ? startT[la] : trans[lb[t - 1] * NK + la];
                if (t == len - 1) numA += endT[la];
            }
        }
    } else if (chunkBase + (tid & 64) < chunkEnd) {   // wave-uniform skip of dead waves
        const int gc = chunkBase + tid;       // global chunk id
        const bool owned = gc < chunkEnd;
        const int t0 = gc * CL;
        const int cE = (len - 1) >> 3;        // end chunk (CL==8)
        float logscale = 0.f, endlog = 0.f;
        bool hasEnd = false;
        h2 wh[9];
        {
            const __fp16 iv = (__fp16)(1.f / NK);
#pragma unroll
            for (int kk = 0; kk < 9; ++kk) { wh[kk].x = iv; wh[kk].y = iv; }
            wh[8].y = (__fp16)0.f;
        }

        if (gc == 0) {   // exact init at t=0 (lt = SP)
            float wf[NK]; float ssum = 0.f;
            const int bdw = (SP >> 2) * CHUNKD;
#pragma unroll
            for (int k = 0; k < 9; ++k) {
                UH u; u.u = expE[bdw + k];
                int n = 2 * k;
                wf[n] = __expf(startT[n]) * (float)u.h.x;
                if (n + 1 < NK) wf[n + 1] = __expf(startT[n + 1]) * (float)u.h.y;
            }
#pragma unroll
            for (int n = 0; n < NK; ++n) ssum += wf[n];
            float r = 1.f / ssum;
            logscale = __logf(ssum);
#pragma unroll
            for (int kk = 0; kk < 8; ++kk)
                wh[kk] = __builtin_amdgcn_cvt_pkrtz(wf[2 * kk] * r, wf[2 * kk + 1] * r);
            wh[8] = __builtin_amdgcn_cvt_pkrtz(wf[16] * r, 0.f);
            if (len == 1) {
                float sd = 0.f;
#pragma unroll
                for (int n = 0; n < NK; ++n) sd += wf[n] * __expf(endT[n]);
                endlog = __logf(sd);
                hasEnd = true;
            }
        }

#pragma unroll 1
        for (int i = 0; i < CL + NW; ++i) {
            int t = t0 - NW + i;
            bool active = (t >= 1);                  // t=0 is init, not an update
            int ta = active ? t : 1;                 // safe staged address
            int lt = ta - ltBase;                    // in [0, NLT) for all lanes
            int bdw = (lt >> 2) * CHUNKD + (lt & 3) * ROWD;
            float ex[NK + 1];
#pragma unroll
            for (int k = 0; k < 9; ++k) {
                UH u; u.u = expE[bdw + k];
                ex[2 * k]     = (float)u.h.x;
                ex[2 * k + 1] = (float)u.h.y;
            }
            if (gc != 0 && t == t0) logscale = 0.f;  // owned growth starts here

            // kk-outer / n-inner: Mg row reads are sequential uniform s_loads
            float acc[NK];
#pragma unroll
            for (int n = 0; n < NK; ++n) acc[n] = 0.f;
#pragma unroll
            for (int kk = 0; kk < 9; ++kk) {
                h2 w = wh[kk];
#pragma unroll
                for (int n = 0; n < NK; ++n) {
                    UH u; u.u = Mg[kk * NK + n];
                    acc[n] = __builtin_amdgcn_fdot2(w, u.h, acc[n], false);
                }
            }
            float wf[NK]; float ssum = 0.f;
#pragma unroll
            for (int n = 0; n < NK; ++n) {
                float w = acc[n] * ex[n];
                wf[n] = w;
                ssum += w;
            }
            float r  = __builtin_amdgcn_rcpf(ssum);
            float lg = __logf(ssum);
            if (active) {
                if (owned && t >= t0 && t == len - 1) {   // end-state tail term
                    float sd = 0.f;
#pragma unroll
                    for (int n = 0; n < NK; ++n) sd += wf[n] * __expf(endT[n]);
                    endlog = logscale + __logf(sd);
                    hasEnd = true;
                }
                logscale += lg;
#pragma unroll
                for (int kk = 0; kk < 8; ++kk)
                    wh[kk] = __builtin_amdgcn_cvt_pkrtz(wf[2 * kk] * r, wf[2 * kk + 1] * r);
                wh[8] = __builtin_amdgcn_cvt_pkrtz(wf[16] * r, 0.f);
            }
        }

        // logZ piece: sum_{c<cE} logN_c + endlog_cE ; only owned chunks contribute.
        zc = owned ? (((gc < cE) ? logscale : 0.f) + (hasEnd ? endlog : 0.f)) : 0.f;
    }

    // ---- phase 3: per-block combine (red aliases expE; chains done reading) ----
    __syncthreads();
    red[tid] = numA - zc;
    __syncthreads();
    for (int k = 128; k >= 1; k >>= 1) { if (tid < k) red[tid] += red[tid + k]; __syncthreads(); }
    if (tid == 0) atomicAdd(out, -red[0] * (1.f / (float)NB));
}

extern "C" void kernel_launch(void* const* d_in, const int* in_sizes, int n_in,
                              void* d_out, int out_size, void* d_ws, size_t ws_size,
                              hipStream_t stream) {
    (void)in_sizes; (void)n_in; (void)out_size; (void)ws_size;
    const float* emis   = (const float*)d_in[0];
    const float* startT = (const float*)d_in[1];
    const float* endT   = (const float*)d_in[2];
    const float* trans  = (const float*)d_in[3];
    const int*   labels = (const int*)d_in[4];
    const int*   attn   = (const int*)d_in[5];
    float* out = (float*)d_out;
    unsigned int* Mg = (unsigned int*)d_ws;                  // 612 B
    int* lens        = (int*)((char*)d_ws + 1024);           // 2048 B

    (void)hipMemsetAsync(d_out, 0, sizeof(float), stream);   // out[0] accumulator
    prep_k<<<NB + 1, 256, 0, stream>>>(trans, attn, Mg, lens);
    crf_fused<<<NB * 2, 256, 0, stream>>>(emis, startT, endT, trans, labels,
                                          lens, Mg, out + 1, out);
}

// Round 6
// 169.556 us; speedup vs baseline: 1.0422x; 1.0422x over previous
//
#include <hip/hip_runtime.h>
#include <cstddef>

#define NB 512
#define NS 2048
#define NK 17
#define CL 8             // owned steps per chunk (one chunk per LANE) -> 1.5 MV/step
#define NW 4             // warmup steps (contraction^4 ~6e-6 << fp16 chain floor)
#define HT 1024          // timesteps per block (half sequence)
#define SP 8             // staged pre-roll before T0 (covers NW; keeps f4 alignment)
#define NLT (HT + SP)    // staged timesteps = 1032
#define CHUNKD 37        // dwords per 4-timestep group: 4 x 9 + 1 pad (37%32=5)
#define ROWD 9           // dwords per timestep row (18 halves: 17 + 1 pad)
#define LDS_DW ((NLT / 4) * CHUNKD)   // 258*37 = 9546 dwords = 38184 B

typedef __fp16 h2 __attribute__((ext_vector_type(2)));
typedef float  f4 __attribute__((ext_vector_type(4)));
union UH { unsigned int u; h2 h; };

// Block 0: Mg[kk*17+n] = half2( exp(T[2kk][n]), exp(T[2kk+1][n]) ), kk=8 hi = 0.
// Blocks 1..NB: lens[b] = sum(attn[b,:])  (mask is a prefix).
__global__ void prep_k(const float* __restrict__ trans, const int* __restrict__ attn,
                       unsigned int* __restrict__ Mg, int* __restrict__ lens) {
    __shared__ int red[4];
    const int tid = threadIdx.x;
    if (blockIdx.x == 0) {
        if (tid < 9 * NK) {
            int kk = tid / NK, n = tid % NK;
            float lo = __expf(trans[(2 * kk) * NK + n]);
            float hi = (kk < 8) ? __expf(trans[(2 * kk + 1) * NK + n]) : 0.f;
            UH u; u.h = __builtin_amdgcn_cvt_pkrtz(lo, hi);
            Mg[tid] = u.u;
        }
        return;
    }
    const int b = blockIdx.x - 1;
    const int4* __restrict__ a4 = (const int4*)(attn + (size_t)b * NS);
    int4 x = a4[tid];
    int4 y = a4[tid + 256];
    int s = x.x + x.y + x.z + x.w + y.x + y.y + y.z + y.w;
#pragma unroll
    for (int off = 32; off >= 1; off >>= 1) s += __shfl_down(s, off, 64);
    if ((tid & 63) == 0) red[tid >> 6] = s;
    __syncthreads();
    if (tid == 0) lens[b] = red[0] + red[1] + red[2] + red[3];
}

// Fused: coalesced staging (emissions->LDS as half(exp(e)) + outE copy, 4-deep
// pipelined) + chain-per-lane scan (lanes 0-127) || numerator (lanes 128-255)
// + per-block logZ piece + atomicAdd.  Dead-timestep work skipped via len.
__global__ __launch_bounds__(256, 4) void crf_fused(
    const float* __restrict__ emis,
    const float* __restrict__ startT,
    const float* __restrict__ endT,
    const float* __restrict__ trans,
    const int*   __restrict__ labels,
    const int*   __restrict__ lens,
    const unsigned int* __restrict__ Mg,
    float*       __restrict__ outE,      // d_out + 1
    float*       __restrict__ out)       // d_out[0], pre-zeroed
{
    __shared__ unsigned int expE[LDS_DW];
    float* red = (float*)expE;           // aliased: expE dead before reduction

    const int tid = threadIdx.x;
    const int b  = blockIdx.x >> 1;
    const int h  = blockIdx.x & 1;
    const int T0 = h << 10;              // h * HT
    const int len = lens[b];             // precomputed in prep_k (scalar load)

    const size_t ebOff = (size_t)b * NS * NK;
    const float* __restrict__ eb = emis + ebOff;
    float*       __restrict__ ob = outE + ebOff;
    const int*   __restrict__ lb = labels + (size_t)b * NS;

    const int endF = (T0 + HT) * NK;
    const int ownF = T0 * NK;            // multiple of 4

    // ---- fast path: block entirely past sequence end -> pure copy, 4-deep ----
    if (T0 >= len) {
        const float* __restrict__ src = eb + ownF;
        float*       __restrict__ dst = ob + ownF;
        const int base = tid * 4;                // 17408 floats = 17 f4 per thread
        f4 r0 = *(const f4*)(src + base);
        f4 r1 = *(const f4*)(src + base + 1024);
        f4 r2 = *(const f4*)(src + base + 2048);
        f4 r3 = *(const f4*)(src + base + 3072);
#pragma unroll
        for (int k = 0; k < 3; ++k) {
            const int o = k * 4096 + base;
            f4 n0 = *(const f4*)(src + o + 4096);
            f4 n1 = *(const f4*)(src + o + 5120);
            f4 n2 = *(const f4*)(src + o + 6144);
            f4 n3 = *(const f4*)(src + o + 7168);
            __builtin_nontemporal_store(r0, (f4*)(dst + o));
            __builtin_nontemporal_store(r1, (f4*)(dst + o + 1024));
            __builtin_nontemporal_store(r2, (f4*)(dst + o + 2048));
            __builtin_nontemporal_store(r3, (f4*)(dst + o + 3072));
            r0 = n0; r1 = n1; r2 = n2; r3 = n3;
        }
        const int o = 12288 + base;
        f4 n0 = *(const f4*)(src + o + 4096);    // last of the 17
        __builtin_nontemporal_store(r0, (f4*)(dst + o));
        __builtin_nontemporal_store(r1, (f4*)(dst + o + 1024));
        __builtin_nontemporal_store(r2, (f4*)(dst + o + 2048));
        __builtin_nontemporal_store(r3, (f4*)(dst + o + 3072));
        __builtin_nontemporal_store(n0, (f4*)(dst + o + 4096));
        return;                          // contribution to loss is exactly 0
    }

    // ---- phase 1: fused copy + staging, 4-deep software pipeline ----
    const int loadT0 = (h == 0) ? 0 : (T0 - SP);
    const int baseF  = loadT0 * NK;      // multiple of 4 -> float4-aligned
    const int lenF   = len * NK;         // stage (exp->LDS) only below this

    {
        int g = baseF + tid * 4;
        // initial (lt, n) via one divide; then tracked incrementally
        int t4  = (int)((unsigned)g / 17u);
        int n4  = g - t4 * 17;
        int lt4 = t4 - (T0 - SP);
        const f4 z = {0.f, 0.f, 0.f, 0.f};
        f4 r0 = (g          < endF) ? *(const f4*)(eb + g         ) : z;
        f4 r1 = (g + 1024   < endF) ? *(const f4*)(eb + g + 1024  ) : z;
        f4 r2 = (g + 2048   < endF) ? *(const f4*)(eb + g + 2048  ) : z;
        f4 r3 = (g + 3072   < endF) ? *(const f4*)(eb + g + 3072  ) : z;
        while (g < endF) {
            f4 nx = (g + 4096 < endF) ? *(const f4*)(eb + g + 4096) : z;  // 4 in flight
            if (g >= ownF) __builtin_nontemporal_store(r0, (f4*)(ob + g));  // passthrough
            if (g < lenF) {                               // live rows only
                float ev[4] = {r0.x, r0.y, r0.z, r0.w};
                int lt = lt4, nn = n4;
#pragma unroll
                for (int u = 0; u < 4; ++u) {
                    int ha = ((lt >> 2) * CHUNKD + (lt & 3) * ROWD) * 2 + nn;
                    ((__fp16*)expE)[ha] = (__fp16)__expf(ev[u]);
                    ++nn; if (nn == 17) { nn = 0; ++lt; }
                }
            }
            // advance 1024 floats = 60 rows + 4 cols
            lt4 += 60; n4 += 4; if (n4 >= 17) { n4 -= 17; ++lt4; }
            r0 = r1; r1 = r2; r2 = r3; r3 = nx;
            g += 1024;
        }
    }
    __syncthreads();

    // ---- phase 2 (role-split, wave-uniform): chains on waves 0-1, numerator on 2-3 ----
    float numA = 0.f, zc = 0.f;

    if (tid >= 128) {
        // numerator: emission gather (L2-warm) + transition / start / end terms
        int t = T0 + (tid - 128);
#pragma unroll
        for (int j = 0; j < 8; ++j, t += 128) {
            if (t < len) {
                int la = lb[t];
                numA += eb[(size_t)t * NK + la];
                numA += (t == 0) ? startT[la] : trans[lb[t - 1] * NK + la];
                if (t == len - 1) numA += endT[la];
            }
        }
    } else if (T0 + ((tid & 64) << 3) < len) {   // wave-uniform: skip fully-dead chain waves
        const int gc = h * 128 + tid;        // global chunk
        const int t0 = gc * CL;
        const int cE = (len - 1) >> 3;       // end chunk (CL==8)
        float logscale = 0.f, endlog = 0.f;
        bool hasEnd = false;
        h2 wh[9];
        {
            const __fp16 iv = (__fp16)(1.f / NK);
#pragma unroll
            for (int kk = 0; kk < 9; ++kk) { wh[kk].x = iv; wh[kk].y = iv; }
            wh[8].y = (__fp16)0.f;
        }

        if (gc == 0) {   // exact init at t=0 (lt = SP)
            float wf[NK]; float ssum = 0.f;
            const int bdw = (SP >> 2) * CHUNKD;
#pragma unroll
            for (int k = 0; k < 9; ++k) {
                UH u; u.u = expE[bdw + k];
                int n = 2 * k;
                wf[n] = __expf(startT[n]) * (float)u.h.x;
                if (n + 1 < NK) wf[n + 1] = __expf(startT[n + 1]) * (float)u.h.y;
            }
#pragma unroll
            for (int n = 0; n < NK; ++n) ssum += wf[n];
            float r = 1.f / ssum;
            logscale = __logf(ssum);
#pragma unroll
            for (int kk = 0; kk < 8; ++kk)
                wh[kk] = __builtin_amdgcn_cvt_pkrtz(wf[2 * kk] * r, wf[2 * kk + 1] * r);
            wh[8] = __builtin_amdgcn_cvt_pkrtz(wf[16] * r, 0.f);
            if (len == 1) {
                float sd = 0.f;
#pragma unroll
                for (int n = 0; n < NK; ++n) sd += wf[n] * __expf(endT[n]);
                endlog = __logf(sd);                 // logscale_old = 0, wf unnormalized
                hasEnd = true;
            }
        }

#pragma unroll 1
        for (int i = 0; i < CL + NW; ++i) {
            int t = t0 - NW + i;
            bool active = (t >= 1);                  // t=0 is init, not an update
            int ta = active ? t : 1;                 // safe staged address for idle lanes
            int lt = ta - (T0 - SP);
            int bdw = (lt >> 2) * CHUNKD + (lt & 3) * ROWD;
            float ex[NK + 1];
#pragma unroll
            for (int k = 0; k < 9; ++k) {            // 9 ds_read_b32
                UH u; u.u = expE[bdw + k];
                ex[2 * k]     = (float)u.h.x;
                ex[2 * k + 1] = (float)u.h.y;
            }
            if (gc != 0 && t == t0) logscale = 0.f;  // owned growth starts here

            // kk-outer / n-inner: Mg row reads are SEQUENTIAL uniform s_loads
            float acc[NK];
#pragma unroll
            for (int n = 0; n < NK; ++n) acc[n] = 0.f;
#pragma unroll
            for (int kk = 0; kk < 9; ++kk) {
                h2 w = wh[kk];
#pragma unroll
                for (int n = 0; n < NK; ++n) {
                    UH u; u.u = Mg[kk * NK + n];
                    acc[n] = __builtin_amdgcn_fdot2(w, u.h, acc[n], false);
                }
            }
            float wf[NK]; float ssum = 0.f;
#pragma unroll
            for (int n = 0; n < NK; ++n) {
                float w = acc[n] * ex[n];
                wf[n] = w;
                ssum += w;
            }
            float r  = __builtin_amdgcn_rcpf(ssum);
            float lg = __logf(ssum);
            if (active) {
                if (t >= t0 && t == len - 1) {       // end-state: record tail term
                    float sd = 0.f;
#pragma unroll
                    for (int n = 0; n < NK; ++n) sd += wf[n] * __expf(endT[n]);
                    endlog = logscale + __logf(sd);  // logscale BEFORE this step's growth
                    hasEnd = true;
                }
                logscale += lg;
#pragma unroll
                for (int kk = 0; kk < 8; ++kk)
                    wh[kk] = __builtin_amdgcn_cvt_pkrtz(wf[2 * kk] * r, wf[2 * kk + 1] * r);
                wh[8] = __builtin_amdgcn_cvt_pkrtz(wf[16] * r, 0.f);
            }
        }

        // logZ piece: sum_{c<cE} logN_c + endlog_cE ; chunks >= cE (non-end) excluded.
        zc = ((gc < cE) ? logscale : 0.f) + (hasEnd ? endlog : 0.f);
    }

    // ---- phase 3: per-block combine (red aliases expE; chains are done reading) ----
    __syncthreads();
    red[tid] = numA - zc;
    __syncthreads();
    for (int k = 128; k >= 1; k >>= 1) { if (tid < k) red[tid] += red[tid + k]; __syncthreads(); }
    if (tid == 0) atomicAdd(out, -red[0] * (1.f / (float)NB));
}

extern "C" void kernel_launch(void* const* d_in, const int* in_sizes, int n_in,
                              void* d_out, int out_size, void* d_ws, size_t ws_size,
                              hipStream_t stream) {
    (void)in_sizes; (void)n_in; (void)out_size; (void)ws_size;
    const float* emis   = (const float*)d_in[0];
    const float* startT = (const float*)d_in[1];
    const float* endT   = (const float*)d_in[2];
    const float* trans  = (const float*)d_in[3];
    const int*   labels = (const int*)d_in[4];
    const int*   attn   = (const int*)d_in[5];
    float* out = (float*)d_out;
    unsigned int* Mg = (unsigned int*)d_ws;                  // 612 B
    int* lens        = (int*)((char*)d_ws + 1024);           // 2048 B

    (void)hipMemsetAsync(d_out, 0, sizeof(float), stream);   // out[0] accumulator
    prep_k<<<NB + 1, 256, 0, stream>>>(trans, attn, Mg, lens);
    crf_fused<<<NB * 2, 256, 0, stream>>>(emis, startT, endT, trans, labels,
                                          lens, Mg, out + 1, out);
}

// Round 7
// 156.606 us; speedup vs baseline: 1.1284x; 1.0827x over previous
//
#include <hip/hip_runtime.h>
#include <cstddef>

#define NB 512
#define NS 2048
#define NK 17
#define CL 8             // owned steps per chunk (one chunk per LANE) -> 1.5 MV/step
#define NW 4             // warmup steps (contraction^4 ~6e-6 << fp16 chain floor)
#define HT 1024          // timesteps per CRF block (half sequence)
#define SP 8             // staged pre-roll before T0 (covers NW; keeps f4 alignment)
#define NLT (HT + SP)    // staged timesteps = 1032
#define CHUNKD 37        // dwords per 4-timestep group: 4 x 9 + 1 pad (37%32=5)
#define ROWD 9           // dwords per timestep row (18 halves: 17 + 1 pad)
#define LDS_DW ((NLT / 4) * CHUNKD)   // 258*37 = 9546 dwords = 38184 B
#define SLABF (HT * NK)  // floats per copy slab = 17408

typedef __fp16 h2 __attribute__((ext_vector_type(2)));
typedef float  f4 __attribute__((ext_vector_type(4)));
union UH { unsigned int u; h2 h; };

// Block 0: Mg[kk*17+n] = half2( exp(T[2kk][n]), exp(T[2kk+1][n]) ), kk=8 hi = 0.
// Blocks 1..NB: lens[b] = sum(attn[b,:])  (mask is a prefix).
__global__ void prep_k(const float* __restrict__ trans, const int* __restrict__ attn,
                       unsigned int* __restrict__ Mg, int* __restrict__ lens) {
    __shared__ int red[4];
    const int tid = threadIdx.x;
    if (blockIdx.x == 0) {
        if (tid < 9 * NK) {
            int kk = tid / NK, n = tid % NK;
            float lo = __expf(trans[(2 * kk) * NK + n]);
            float hi = (kk < 8) ? __expf(trans[(2 * kk + 1) * NK + n]) : 0.f;
            UH u; u.h = __builtin_amdgcn_cvt_pkrtz(lo, hi);
            Mg[tid] = u.u;
        }
        return;
    }
    const int b = blockIdx.x - 1;
    const int4* __restrict__ a4 = (const int4*)(attn + (size_t)b * NS);
    int4 x = a4[tid];
    int4 y = a4[tid + 256];
    int s = x.x + x.y + x.z + x.w + y.x + y.y + y.z + y.w;
#pragma unroll
    for (int off = 32; off >= 1; off >>= 1) s += __shfl_down(s, off, 64);
    if ((tid & 63) == 0) red[tid >> 6] = s;
    __syncthreads();
    if (tid == 0) lens[b] = red[0] + red[1] + red[2] + red[3];
}

// Block-specialized: blocks [0, 2NB) = CRF compute (stage live rows -> LDS,
// chain scan + numerator, no copy); blocks [2NB, 4NB) = pure outE slab copy.
// CRF blocks first -> copy blocks backfill as CRF blocks retire, overlapping
// HBM streaming with chain VALU work instead of phase-lockstep.
__global__ __launch_bounds__(256, 4) void crf_fused(
    const float* __restrict__ emis,
    const float* __restrict__ startT,
    const float* __restrict__ endT,
    const float* __restrict__ trans,
    const int*   __restrict__ labels,
    const int*   __restrict__ lens,
    const unsigned int* __restrict__ Mg,
    float*       __restrict__ outE,      // d_out + 1
    float*       __restrict__ out)       // d_out[0], pre-zeroed
{
    __shared__ unsigned int expE[LDS_DW];
    float* red = (float*)expE;           // aliased: expE dead before reduction

    const int tid = threadIdx.x;

    // ---- copy blocks: fixed 1024-row slab, 17 f4/thread, 4-deep rotation ----
    if (blockIdx.x >= NB * 2) {
        const size_t off = (size_t)(blockIdx.x - NB * 2) * SLABF;
        const float* __restrict__ src = emis + off;
        float*       __restrict__ dst = outE + off;
        const int base = tid * 4;                // 17408 floats = 17 f4 per thread
        f4 r0 = *(const f4*)(src + base);
        f4 r1 = *(const f4*)(src + base + 1024);
        f4 r2 = *(const f4*)(src + base + 2048);
        f4 r3 = *(const f4*)(src + base + 3072);
#pragma unroll
        for (int k = 0; k < 3; ++k) {
            const int o = k * 4096 + base;
            f4 n0 = *(const f4*)(src + o + 4096);
            f4 n1 = *(const f4*)(src + o + 5120);
            f4 n2 = *(const f4*)(src + o + 6144);
            f4 n3 = *(const f4*)(src + o + 7168);
            __builtin_nontemporal_store(r0, (f4*)(dst + o));
            __builtin_nontemporal_store(r1, (f4*)(dst + o + 1024));
            __builtin_nontemporal_store(r2, (f4*)(dst + o + 2048));
            __builtin_nontemporal_store(r3, (f4*)(dst + o + 3072));
            r0 = n0; r1 = n1; r2 = n2; r3 = n3;
        }
        const int o = 12288 + base;
        f4 n0 = *(const f4*)(src + o + 4096);    // last of the 17
        __builtin_nontemporal_store(r0, (f4*)(dst + o));
        __builtin_nontemporal_store(r1, (f4*)(dst + o + 1024));
        __builtin_nontemporal_store(r2, (f4*)(dst + o + 2048));
        __builtin_nontemporal_store(r3, (f4*)(dst + o + 3072));
        __builtin_nontemporal_store(n0, (f4*)(dst + o + 4096));
        return;
    }

    // ---- CRF blocks ----
    const int b  = blockIdx.x >> 1;
    const int h  = blockIdx.x & 1;
    const int T0 = h << 10;              // h * HT
    const int len = lens[b];             // precomputed in prep_k (scalar load)

    if (T0 >= len) return;               // dead half: zero contribution, vacate slot

    const size_t ebOff = (size_t)b * NS * NK;
    const float* __restrict__ eb = emis + ebOff;
    const int*   __restrict__ lb = labels + (size_t)b * NS;

    // ---- phase 1: stage live rows [startT0, Tstop) -> LDS half(exp(e)) ----
    {
        const int startF = ((h == 0) ? 0 : (T0 - SP)) * NK;   // multiple of 4
        const int Tstop  = (len < T0 + HT) ? len : (T0 + HT);
        const int stopF  = Tstop * NK;
        int g = startF + tid * 4;
        int t4  = (int)((unsigned)g / 17u);
        int n4  = g - t4 * 17;
        int lt4 = t4 - (T0 - SP);
        f4 v = {0.f, 0.f, 0.f, 0.f};
        if (g < stopF) v = *(const f4*)(eb + g);
        while (g < stopF) {
            const int gn = g + 1024;
            f4 vn = v;
            if (gn < stopF) vn = *(const f4*)(eb + gn);   // prefetch stays in flight
            float ev[4] = {v.x, v.y, v.z, v.w};
            int lt = lt4, nn = n4;
#pragma unroll
            for (int u = 0; u < 4; ++u) {
                if (g + u < stopF) {
                    int ha = ((lt >> 2) * CHUNKD + (lt & 3) * ROWD) * 2 + nn;
                    ((__fp16*)expE)[ha] = (__fp16)__expf(ev[u]);
                }
                ++nn; if (nn == 17) { nn = 0; ++lt; }
            }
            lt4 += 60; n4 += 4; if (n4 >= 17) { n4 -= 17; ++lt4; }   // +1024 floats
            v = vn; g = gn;
        }
    }
    __syncthreads();

    // ---- phase 2 (role-split, wave-uniform): chains on waves 0-1, numerator on 2-3 ----
    float numA = 0.f, zc = 0.f;

    if (tid >= 128) {
        // numerator: emission gather (L2-warm) + transition / start / end terms
        int t = T0 + (tid - 128);
#pragma unroll
        for (int j = 0; j < 8; ++j, t += 128) {
            if (t < len) {
                int la = lb[t];
                numA += eb[(size_t)t * NK + la];
                numA += (t == 0) ? startT[la] : trans[lb[t - 1] * NK + la];
                if (t == len - 1) numA += endT[la];
            }
        }
    } else if (T0 + ((tid & 64) << 3) < len) {   // wave-uniform: skip fully-dead chain waves
        const int gc = h * 128 + tid;        // global chunk
        const int t0 = gc * CL;
        const int cE = (len - 1) >> 3;       // end chunk (CL==8)
        float logscale = 0.f, endlog = 0.f;
        bool hasEnd = false;
        h2 wh[9];
        {
            const __fp16 iv = (__fp16)(1.f / NK);
#pragma unroll
            for (int kk = 0; kk < 9; ++kk) { wh[kk].x = iv; wh[kk].y = iv; }
            wh[8].y = (__fp16)0.f;
        }

        if (gc == 0) {   // exact init at t=0 (lt = SP)
            float wf[NK]; float ssum = 0.f;
            const int bdw = (SP >> 2) * CHUNKD;
#pragma unroll
            for (int k = 0; k < 9; ++k) {
                UH u; u.u = expE[bdw + k];
                int n = 2 * k;
                wf[n] = __expf(startT[n]) * (float)u.h.x;
                if (n + 1 < NK) wf[n + 1] = __expf(startT[n + 1]) * (float)u.h.y;
            }
#pragma unroll
            for (int n = 0; n < NK; ++n) ssum += wf[n];
            float r = 1.f / ssum;
            logscale = __logf(ssum);
#pragma unroll
            for (int kk = 0; kk < 8; ++kk)
                wh[kk] = __builtin_amdgcn_cvt_pkrtz(wf[2 * kk] * r, wf[2 * kk + 1] * r);
            wh[8] = __builtin_amdgcn_cvt_pkrtz(wf[16] * r, 0.f);
            if (len == 1) {
                float sd = 0.f;
#pragma unroll
                for (int n = 0; n < NK; ++n) sd += wf[n] * __expf(endT[n]);
                endlog = __logf(sd);                 // logscale_old = 0, wf unnormalized
                hasEnd = true;
            }
        }

#pragma unroll 1
        for (int i = 0; i < CL + NW; ++i) {
            int t = t0 - NW + i;
            bool active = (t >= 1);                  // t=0 is init, not an update
            int ta = active ? t : 1;                 // safe staged address for idle lanes
            int lt = ta - (T0 - SP);
            int bdw = (lt >> 2) * CHUNKD + (lt & 3) * ROWD;
            float ex[NK + 1];
#pragma unroll
            for (int k = 0; k < 9; ++k) {            // 9 ds_read_b32
                UH u; u.u = expE[bdw + k];
                ex[2 * k]     = (float)u.h.x;
                ex[2 * k + 1] = (float)u.h.y;
            }
            if (gc != 0 && t == t0) logscale = 0.f;  // owned growth starts here

            // kk-outer / n-inner: Mg row reads are SEQUENTIAL uniform s_loads
            float acc[NK];
#pragma unroll
            for (int n = 0; n < NK; ++n) acc[n] = 0.f;
#pragma unroll
            for (int kk = 0; kk < 9; ++kk) {
                h2 w = wh[kk];
#pragma unroll
                for (int n = 0; n < NK; ++n) {
                    UH u; u.u = Mg[kk * NK + n];
                    acc[n] = __builtin_amdgcn_fdot2(w, u.h, acc[n], false);
                }
            }
            float wf[NK]; float ssum = 0.f;
#pragma unroll
            for (int n = 0; n < NK; ++n) {
                float w = acc[n] * ex[n];
                wf[n] = w;
                ssum += w;
            }
            float r  = __builtin_amdgcn_rcpf(ssum);
            float lg = __logf(ssum);
            if (active) {
                if (t >= t0 && t == len - 1) {       // end-state: record tail term
                    float sd = 0.f;
#pragma unroll
                    for (int n = 0; n < NK; ++n) sd += wf[n] * __expf(endT[n]);
                    endlog = logscale + __logf(sd);  // logscale BEFORE this step's growth
                    hasEnd = true;
                }
                logscale += lg;
#pragma unroll
                for (int kk = 0; kk < 8; ++kk)
                    wh[kk] = __builtin_amdgcn_cvt_pkrtz(wf[2 * kk] * r, wf[2 * kk + 1] * r);
                wh[8] = __builtin_amdgcn_cvt_pkrtz(wf[16] * r, 0.f);
            }
        }

        // logZ piece: sum_{c<cE} logN_c + endlog_cE ; chunks >= cE (non-end) excluded.
        zc = ((gc < cE) ? logscale : 0.f) + (hasEnd ? endlog : 0.f);
    }

    // ---- phase 3: per-block combine (red aliases expE; chains are done reading) ----
    __syncthreads();
    red[tid] = numA - zc;
    __syncthreads();
    for (int k = 128; k >= 1; k >>= 1) { if (tid < k) red[tid] += red[tid + k]; __syncthreads(); }
    if (tid == 0) atomicAdd(out, -red[0] * (1.f / (float)NB));
}

extern "C" void kernel_launch(void* const* d_in, const int* in_sizes, int n_in,
                              void* d_out, int out_size, void* d_ws, size_t ws_size,
                              hipStream_t stream) {
    (void)in_sizes; (void)n_in; (void)out_size; (void)ws_size;
    const float* emis   = (const float*)d_in[0];
    const float* startT = (const float*)d_in[1];
    const float* endT   = (const float*)d_in[2];
    const float* trans  = (const float*)d_in[3];
    const int*   labels = (const int*)d_in[4];
    const int*   attn   = (const int*)d_in[5];
    float* out = (float*)d_out;
    unsigned int* Mg = (unsigned int*)d_ws;                  // 612 B
    int* lens        = (int*)((char*)d_ws + 1024);           // 2048 B

    (void)hipMemsetAsync(d_out, 0, sizeof(float), stream);   // out[0] accumulator
    prep_k<<<NB + 1, 256, 0, stream>>>(trans, attn, Mg, lens);
    crf_fused<<<NB * 4, 256, 0, stream>>>(emis, startT, endT, trans, labels,
                                          lens, Mg, out + 1, out);
}